// Round 4
// baseline (793.594 us; speedup 1.0000x reference)
//
#include <hip/hip_runtime.h>
#include <cstddef>
#include <cstdint>

#define TMAX 512
#define HDIM 64

typedef _Float16 half2v __attribute__((ext_vector_type(2)));

__device__ __forceinline__ float fsig(float x) {
    x = fminf(fmaxf(x, -30.f), 30.f);
    float e = __expf(-x);
    return __builtin_amdgcn_rcpf(1.f + e);
}
__device__ __forceinline__ float ftanh(float x) {
    x = fminf(fmaxf(x, -15.f), 15.f);      // tanh(15)==1 in fp32; avoid inf/inf
    float e = __expf(2.f * x);
    return (e - 1.f) * __builtin_amdgcn_rcpf(e + 1.f);
}

#if __has_builtin(__builtin_amdgcn_fdot2)
__device__ __forceinline__ float dot2acc(half2v a, half2v b, float c) {
    return __builtin_amdgcn_fdot2(a, b, c, false);   // v_dot2_f32_f16
}
#else
__device__ __forceinline__ float dot2acc(half2v a, half2v b, float c) {
    return fmaf((float)a.y, (float)b.y, fmaf((float)a.x, (float)b.x, c));
}
#endif

// One wave (64 lanes) per batch row; lane u owns hidden unit u and computes
// gates u, u+64, u+128, u+192. No barriers anywhere (h exchanged via a
// 128-byte wave-private LDS buffer, broadcast reads).
//
// amdgpu_waves_per_eu(1,2): the grid is 2048 waves = exactly 2 waves/SIMD
// device-wide, so occupancy above 2 waves/EU is worthless. Capping the
// allocator's occupancy target at 2 gives it the full 256-VGPR budget and
// removes its incentive to spill the 128-VGPR weight array (rounds 2/3:
// VGPR_Count 96/112 proved weights were reloaded from L2/scratch each step).
__global__
__attribute__((amdgpu_flat_work_group_size(64, 64)))
__attribute__((amdgpu_waves_per_eu(1, 2)))
void lstm_wave_kernel(const float* __restrict__ ctx_g,   // (B, T)
                      const float* __restrict__ Wih_e,   // (256,1)
                      const float* __restrict__ Whh_e,   // (256,64)
                      const float* __restrict__ bih_e,
                      const float* __restrict__ bhh_e,
                      const float* __restrict__ Wih_d,
                      const float* __restrict__ Whh_d,
                      const float* __restrict__ bih_d,
                      const float* __restrict__ bhh_d,
                      const float* __restrict__ Whead,   // (1,64)
                      const float* __restrict__ bhead,   // (1,)
                      float* __restrict__ out,           // (B, n_steps)
                      int T, int n_steps)
{
    __shared__ __align__(16) float    ctx_s[TMAX];
    __shared__ __align__(16) _Float16 h_s[HDIM];

    const int lane = threadIdx.x;           // 0..63 == hidden unit
    const int row  = blockIdx.x;            // batch row

    const float* ctxr = ctx_g + (size_t)row * T;
    for (int t = lane; t < T; t += 64) ctx_s[t] = ctxr[t];

    uint32_t wbits[4][32];                   // fp16-packed W_hh rows, 128 VGPRs
    float    wih[4], bias[4];

    // ---- fill + pin encoder weights ----
    #pragma unroll
    for (int g = 0; g < 4; ++g) {
        const int j = lane + (g << 6);
        const float2* wr = reinterpret_cast<const float2*>(Whh_e + (size_t)j * HDIM);
        #pragma unroll
        for (int k = 0; k < 32; ++k) {
            float2 wv = wr[k];
            half2v hw = half2v{(_Float16)wv.x, (_Float16)wv.y};
            wbits[g][k] = __builtin_bit_cast(uint32_t, hw);
        }
        wih[g]  = Wih_e[j];
        bias[g] = bih_e[j] + bhh_e[j];
    }
    #pragma unroll
    for (int g = 0; g < 4; ++g) {
        #pragma unroll
        for (int k = 0; k < 32; ++k) asm volatile("" : "+v"(wbits[g][k]));
        asm volatile("" : "+v"(wih[g]), "+v"(bias[g]));
    }

    float c = 0.f, h = 0.f;
    h_s[lane] = (_Float16)0.f;

    // ---------------- encoder: T sequential steps ----------------
    for (int t = 0; t < T; ++t) {
        const float x = ctx_s[t];
        float aA[4], aB[4];
        #pragma unroll
        for (int g = 0; g < 4; ++g) { aA[g] = fmaf(x, wih[g], bias[g]); aB[g] = 0.f; }
        #pragma unroll
        for (int ch = 0; ch < 8; ++ch) {     // 8 x ds_read_b128 (broadcast)
            uint4 hv = reinterpret_cast<const uint4*>(h_s)[ch];
            half2v hp[4];
            hp[0] = __builtin_bit_cast(half2v, hv.x);
            hp[1] = __builtin_bit_cast(half2v, hv.y);
            hp[2] = __builtin_bit_cast(half2v, hv.z);
            hp[3] = __builtin_bit_cast(half2v, hv.w);
            #pragma unroll
            for (int e = 0; e < 4; ++e) {
                const int k = ch * 4 + e;
                #pragma unroll
                for (int g = 0; g < 4; ++g) {
                    half2v wv = __builtin_bit_cast(half2v, wbits[g][k]);
                    if (ch < 4) aA[g] = dot2acc(wv, hp[e], aA[g]);
                    else        aB[g] = dot2acc(wv, hp[e], aB[g]);
                }
            }
        }
        const float ig = fsig(aA[0] + aB[0]);
        const float fg = fsig(aA[1] + aB[1]);
        const float gg = ftanh(aA[2] + aB[2]);
        const float og = fsig(aA[3] + aB[3]);
        c = fmaf(fg, c, ig * gg);
        h = og * ftanh(c);
        h_s[lane] = (_Float16)h;             // visible to the wave next step
    }

    // ---- fill + pin decoder weights ----
    #pragma unroll
    for (int g = 0; g < 4; ++g) {
        const int j = lane + (g << 6);
        const float2* wr = reinterpret_cast<const float2*>(Whh_d + (size_t)j * HDIM);
        #pragma unroll
        for (int k = 0; k < 32; ++k) {
            float2 wv = wr[k];
            half2v hw = half2v{(_Float16)wv.x, (_Float16)wv.y};
            wbits[g][k] = __builtin_bit_cast(uint32_t, hw);
        }
        wih[g]  = Wih_d[j];
        bias[g] = bih_d[j] + bhh_d[j];
    }
    #pragma unroll
    for (int g = 0; g < 4; ++g) {
        #pragma unroll
        for (int k = 0; k < 32; ++k) asm volatile("" : "+v"(wbits[g][k]));
        asm volatile("" : "+v"(wih[g]), "+v"(bias[g]));
    }
    const float wh = Whead[lane];
    const float bh = bhead[0];
    float z = ctx_s[T - 1];                  // z0 = context[:, -1]

    // ---------------- decoder: n_steps sequential steps ----------------
    for (int s = 0; s < n_steps; ++s) {
        float aA[4], aB[4];
        #pragma unroll
        for (int g = 0; g < 4; ++g) { aA[g] = fmaf(z, wih[g], bias[g]); aB[g] = 0.f; }
        #pragma unroll
        for (int ch = 0; ch < 8; ++ch) {
            uint4 hv = reinterpret_cast<const uint4*>(h_s)[ch];
            half2v hp[4];
            hp[0] = __builtin_bit_cast(half2v, hv.x);
            hp[1] = __builtin_bit_cast(half2v, hv.y);
            hp[2] = __builtin_bit_cast(half2v, hv.z);
            hp[3] = __builtin_bit_cast(half2v, hv.w);
            #pragma unroll
            for (int e = 0; e < 4; ++e) {
                const int k = ch * 4 + e;
                #pragma unroll
                for (int g = 0; g < 4; ++g) {
                    half2v wv = __builtin_bit_cast(half2v, wbits[g][k]);
                    if (ch < 4) aA[g] = dot2acc(wv, hp[e], aA[g]);
                    else        aB[g] = dot2acc(wv, hp[e], aB[g]);
                }
            }
        }
        const float ig = fsig(aA[0] + aB[0]);
        const float fg = fsig(aA[1] + aB[1]);
        const float gg = ftanh(aA[2] + aB[2]);
        const float og = fsig(aA[3] + aB[3]);
        c = fmaf(fg, c, ig * gg);
        h = og * ftanh(c);
        h_s[lane] = (_Float16)h;

        // head: z = sum_u h[u]*Whead[u] + b (fp32 butterfly, wave-uniform z)
        float p = h * wh;
        #pragma unroll
        for (int off = 32; off >= 1; off >>= 1)
            p += __shfl_xor(p, off);
        z = p + bh;
        if (lane == 0) out[(size_t)row * n_steps + s] = z;
    }
}

extern "C" void kernel_launch(void* const* d_in, const int* in_sizes, int n_in,
                              void* d_out, int out_size, void* d_ws, size_t ws_size,
                              hipStream_t stream)
{
    const float* ctx   = (const float*)d_in[0];
    const float* Wih_e = (const float*)d_in[1];
    const float* Whh_e = (const float*)d_in[2];
    const float* bih_e = (const float*)d_in[3];
    const float* bhh_e = (const float*)d_in[4];
    const float* Wih_d = (const float*)d_in[5];
    const float* Whh_d = (const float*)d_in[6];
    const float* bih_d = (const float*)d_in[7];
    const float* bhh_d = (const float*)d_in[8];
    const float* Whead = (const float*)d_in[9];
    const float* bhead = (const float*)d_in[10];
    float* out = (float*)d_out;

    const int B = 2048;                 // fixed by the harness setup
    const int T = in_sizes[0] / B;      // 512
    const int n_steps = out_size / B;   // 256

    lstm_wave_kernel<<<dim3(B), dim3(64), 0, stream>>>(
        ctx, Wih_e, Whh_e, bih_e, bhh_e,
        Wih_d, Whh_d, bih_d, bhh_d,
        Whead, bhead, out, T, n_steps);
}

// Round 5
// 785.836 us; speedup vs baseline: 1.0099x; 1.0099x over previous
//
#include <hip/hip_runtime.h>
#include <cstddef>
#include <cstdint>

#define TMAX 512
#define HDIM 64

typedef _Float16 half2v __attribute__((ext_vector_type(2)));

__device__ __forceinline__ float fsig(float x) {
    x = fminf(fmaxf(x, -30.f), 30.f);
    float e = __expf(-x);
    return __builtin_amdgcn_rcpf(1.f + e);
}
__device__ __forceinline__ float ftanh(float x) {
    x = fminf(fmaxf(x, -15.f), 15.f);      // tanh(15)==1 in fp32; avoid inf/inf
    float e = __expf(2.f * x);
    return (e - 1.f) * __builtin_amdgcn_rcpf(e + 1.f);
}

#if __has_builtin(__builtin_amdgcn_fdot2)
__device__ __forceinline__ float dot2acc(half2v a, half2v b, float c) {
    return __builtin_amdgcn_fdot2(a, b, c, false);   // v_dot2_f32_f16
}
#else
__device__ __forceinline__ float dot2acc(half2v a, half2v b, float c) {
    return fmaf((float)a.y, (float)b.y, fmaf((float)a.x, (float)b.x, c));
}
#endif

// Block = 128 threads = 2 waves = ONE batch row.
//   wave A (wid=0): lane u owns gate rows u (i) and u+64 (f); owns c, does the
//                   cell update, h write, and the decoder head reduce.
//   wave B (wid=1): lane u owns gate rows u+128 (g) and u+192 (o); publishes
//                   tanh(g), sigmoid(o) through LDS.
// Per-wave weight footprint: 2 rows x 32 packed fp16 pairs = 64 VGPRs -> fits
// the allocator's natural 128-reg budget (rounds 2-4 proved it will NOT hold
// 128 weight VGPRs per wave). 4096 waves total = 4 waves/SIMD.
__global__ __launch_bounds__(128, 4)
void lstm_2wave_kernel(const float* __restrict__ ctx_g,   // (B, T)
                       const float* __restrict__ Wih_e,   // (256,1)
                       const float* __restrict__ Whh_e,   // (256,64)
                       const float* __restrict__ bih_e,
                       const float* __restrict__ bhh_e,
                       const float* __restrict__ Wih_d,
                       const float* __restrict__ Whh_d,
                       const float* __restrict__ bih_d,
                       const float* __restrict__ bhh_d,
                       const float* __restrict__ Whead,   // (1,64)
                       const float* __restrict__ bhead,   // (1,)
                       float* __restrict__ out,           // (B, n_steps)
                       int T, int n_steps)
{
    __shared__ __align__(16) float    ctx_s[TMAX];
    __shared__ __align__(16) _Float16 h_s[HDIM];
    __shared__ __align__(16) float2   exch[HDIM];   // (tanh(g), sig(o)) per unit
    __shared__ float z_s;

    const int tid  = threadIdx.x;
    const int u    = tid & 63;          // hidden unit
    const int wid  = tid >> 6;          // 0 = wave A, 1 = wave B
    const int row  = blockIdx.x;        // batch row

    const float* ctxr = ctx_g + (size_t)row * T;
    for (int t = tid; t < T; t += 128) ctx_s[t] = ctxr[t];

    const int j0 = u + (wid << 7);      // A: u      | B: u+128
    const int j1 = j0 + 64;             // A: u+64   | B: u+192

    uint32_t w0[32], w1[32];            // fp16-packed W_hh rows (64 VGPRs)
    float wih0, wih1, b0, b1;

    // ---- encoder weights ----
    {
        const float2* r0 = reinterpret_cast<const float2*>(Whh_e + (size_t)j0 * HDIM);
        const float2* r1 = reinterpret_cast<const float2*>(Whh_e + (size_t)j1 * HDIM);
        #pragma unroll
        for (int k = 0; k < 32; ++k) {
            float2 a = r0[k], b = r1[k];
            w0[k] = __builtin_bit_cast(uint32_t, half2v{(_Float16)a.x, (_Float16)a.y});
            w1[k] = __builtin_bit_cast(uint32_t, half2v{(_Float16)b.x, (_Float16)b.y});
        }
        wih0 = Wih_e[j0];  wih1 = Wih_e[j1];
        b0 = bih_e[j0] + bhh_e[j0];
        b1 = bih_e[j1] + bhh_e[j1];
    }

    float c = 0.f;
    if (wid == 0) h_s[u] = (_Float16)0.f;
    __syncthreads();

    // ---------------- encoder: T sequential steps ----------------
    for (int t = 0; t < T; ++t) {
        const float x = ctx_s[t];
        float a0A = fmaf(x, wih0, b0), a0B = 0.f;
        float a1A = fmaf(x, wih1, b1), a1B = 0.f;
        #pragma unroll
        for (int ch = 0; ch < 8; ++ch) {         // broadcast ds_read_b128
            uint4 hv = reinterpret_cast<const uint4*>(h_s)[ch];
            half2v hp[4];
            hp[0] = __builtin_bit_cast(half2v, hv.x);
            hp[1] = __builtin_bit_cast(half2v, hv.y);
            hp[2] = __builtin_bit_cast(half2v, hv.z);
            hp[3] = __builtin_bit_cast(half2v, hv.w);
            #pragma unroll
            for (int e = 0; e < 4; ++e) {
                const int k = ch * 4 + e;
                half2v wv0 = __builtin_bit_cast(half2v, w0[k]);
                half2v wv1 = __builtin_bit_cast(half2v, w1[k]);
                if (ch < 4) { a0A = dot2acc(wv0, hp[e], a0A); a1A = dot2acc(wv1, hp[e], a1A); }
                else        { a0B = dot2acc(wv0, hp[e], a0B); a1B = dot2acc(wv1, hp[e], a1B); }
            }
        }
        const float a0 = a0A + a0B;
        const float a1 = a1A + a1B;
        if (wid) {                                // B: publish tanh(g), sig(o)
            exch[u] = make_float2(ftanh(a0), fsig(a1));
        }
        __syncthreads();
        if (!wid) {                               // A: cell update
            const float ii = fsig(a0);
            const float ff = fsig(a1);
            const float2 go = exch[u];
            c = fmaf(ff, c, ii * go.x);
            h_s[u] = (_Float16)(go.y * ftanh(c));
        }
        __syncthreads();
    }

    // ---- decoder weights ----
    {
        const float2* r0 = reinterpret_cast<const float2*>(Whh_d + (size_t)j0 * HDIM);
        const float2* r1 = reinterpret_cast<const float2*>(Whh_d + (size_t)j1 * HDIM);
        #pragma unroll
        for (int k = 0; k < 32; ++k) {
            float2 a = r0[k], b = r1[k];
            w0[k] = __builtin_bit_cast(uint32_t, half2v{(_Float16)a.x, (_Float16)a.y});
            w1[k] = __builtin_bit_cast(uint32_t, half2v{(_Float16)b.x, (_Float16)b.y});
        }
        wih0 = Wih_d[j0];  wih1 = Wih_d[j1];
        b0 = bih_d[j0] + bhh_d[j0];
        b1 = bih_d[j1] + bhh_d[j1];
    }
    const float wh = Whead[u];
    const float bh = bhead[0];
    float z = ctx_s[T - 1];                       // z0 = context[:, -1]

    // ---------------- decoder: n_steps sequential steps ----------------
    for (int s = 0; s < n_steps; ++s) {
        float a0A = fmaf(z, wih0, b0), a0B = 0.f;
        float a1A = fmaf(z, wih1, b1), a1B = 0.f;
        #pragma unroll
        for (int ch = 0; ch < 8; ++ch) {
            uint4 hv = reinterpret_cast<const uint4*>(h_s)[ch];
            half2v hp[4];
            hp[0] = __builtin_bit_cast(half2v, hv.x);
            hp[1] = __builtin_bit_cast(half2v, hv.y);
            hp[2] = __builtin_bit_cast(half2v, hv.z);
            hp[3] = __builtin_bit_cast(half2v, hv.w);
            #pragma unroll
            for (int e = 0; e < 4; ++e) {
                const int k = ch * 4 + e;
                half2v wv0 = __builtin_bit_cast(half2v, w0[k]);
                half2v wv1 = __builtin_bit_cast(half2v, w1[k]);
                if (ch < 4) { a0A = dot2acc(wv0, hp[e], a0A); a1A = dot2acc(wv1, hp[e], a1A); }
                else        { a0B = dot2acc(wv0, hp[e], a0B); a1B = dot2acc(wv1, hp[e], a1B); }
            }
        }
        const float a0 = a0A + a0B;
        const float a1 = a1A + a1B;
        if (wid) {
            exch[u] = make_float2(ftanh(a0), fsig(a1));
        }
        __syncthreads();
        if (!wid) {
            const float ii = fsig(a0);
            const float ff = fsig(a1);
            const float2 go = exch[u];
            c = fmaf(ff, c, ii * go.x);
            const float h = go.y * ftanh(c);
            h_s[u] = (_Float16)h;
            // head: z = sum_u h[u]*Whead[u] + b (fp32 butterfly on wave A)
            float p = h * wh;
            #pragma unroll
            for (int off = 32; off >= 1; off >>= 1)
                p += __shfl_xor(p, off);
            if (u == 0) {
                const float zn = p + bh;
                z_s = zn;
                out[(size_t)row * n_steps + s] = zn;
            }
        }
        __syncthreads();
        z = z_s;                                  // wave-uniform for both waves
    }
}

extern "C" void kernel_launch(void* const* d_in, const int* in_sizes, int n_in,
                              void* d_out, int out_size, void* d_ws, size_t ws_size,
                              hipStream_t stream)
{
    const float* ctx   = (const float*)d_in[0];
    const float* Wih_e = (const float*)d_in[1];
    const float* Whh_e = (const float*)d_in[2];
    const float* bih_e = (const float*)d_in[3];
    const float* bhh_e = (const float*)d_in[4];
    const float* Wih_d = (const float*)d_in[5];
    const float* Whh_d = (const float*)d_in[6];
    const float* bih_d = (const float*)d_in[7];
    const float* bhh_d = (const float*)d_in[8];
    const float* Whead = (const float*)d_in[9];
    const float* bhead = (const float*)d_in[10];
    float* out = (float*)d_out;

    const int B = 2048;                 // fixed by the harness setup
    const int T = in_sizes[0] / B;      // 512
    const int n_steps = out_size / B;   // 256

    lstm_2wave_kernel<<<dim3(B), dim3(128), 0, stream>>>(
        ctx, Wih_e, Whh_e, bih_e, bhh_e,
        Wih_d, Whh_d, bih_d, bhh_d,
        Whead, bhead, out, T, n_steps);
}